// Round 9
// baseline (621.117 us; speedup 1.0000x reference)
//
#include <hip/hip_runtime.h>

#define N_NODES 50000
#define E_EDGES 800000
#define E2 (E_EDGES + N_NODES)
#define HC 256
#define NHEAD 4
#define GG 128
#define DENSE 64
#define NCLS 2
#define BN_EPS 1e-5f
#define NEG_SLOPE 0.2f
#define NEG_BIG -1e30f

typedef __attribute__((ext_vector_type(8))) short bf16x8;
typedef __attribute__((ext_vector_type(4))) float f32x4;

__device__ __forceinline__ unsigned short f2bf(float f) {
    unsigned int u = __float_as_uint(f);
    u = (u + 0x7FFFu + ((u >> 16) & 1u)) >> 16;
    return (unsigned short)u;
}
__device__ __forceinline__ float bf2f(unsigned short h) {
    return __uint_as_float(((unsigned int)h) << 16);
}
__device__ __forceinline__ float lrelu(float e) {
    return (e >= 0.f) ? e : NEG_SLOPE * e;
}
// accumulate 8 bf16 (packed in uint4) * w into acc[8]; lo=shift, hi=mask (no cvt)
__device__ __forceinline__ void accum8(float acc[8], uint4 v, float w) {
    acc[0] = fmaf(w, __uint_as_float(v.x << 16), acc[0]);
    acc[1] = fmaf(w, __uint_as_float(v.x & 0xffff0000u), acc[1]);
    acc[2] = fmaf(w, __uint_as_float(v.y << 16), acc[2]);
    acc[3] = fmaf(w, __uint_as_float(v.y & 0xffff0000u), acc[3]);
    acc[4] = fmaf(w, __uint_as_float(v.z << 16), acc[4]);
    acc[5] = fmaf(w, __uint_as_float(v.z & 0xffff0000u), acc[5]);
    acc[6] = fmaf(w, __uint_as_float(v.w << 16), acc[6]);
    acc[7] = fmaf(w, __uint_as_float(v.w & 0xffff0000u), acc[7]);
}

// ---------------- fp32 -> bf16 conversion (8 elems/thread) ----------------
__global__ __launch_bounds__(256) void convert_bf16_kernel(const float* __restrict__ in,
                                                           unsigned short* __restrict__ out,
                                                           int n8) {
    int i = blockIdx.x * blockDim.x + threadIdx.x;
    if (i >= n8) return;
    const float4* p = reinterpret_cast<const float4*>(in + (size_t)i * 8);
    float4 a = p[0], b = p[1];
    ushort4 lo = make_ushort4(f2bf(a.x), f2bf(a.y), f2bf(a.z), f2bf(a.w));
    ushort4 hi = make_ushort4(f2bf(b.x), f2bf(b.y), f2bf(b.z), f2bf(b.w));
    ushort4* q = reinterpret_cast<ushort4*>(out + (size_t)i * 8);
    q[0] = lo; q[1] = hi;
}

// ---------------- pack W [256,256] fp32 into MFMA b-fragment order, bf16 ----------------
__global__ __launch_bounds__(64) void pack_b_kernel(const float* __restrict__ W,
                                                    unsigned short* __restrict__ Bpk) {
    int l = threadIdx.x;
    int g = blockIdx.x;
    int ks = g >> 4, ct = g & 15;
    int col = ct * 16 + (l & 15);
    int k0 = ks * 32 + (l >> 4) * 8;
    unsigned short v[8];
#pragma unroll
    for (int j = 0; j < 8; ++j) v[j] = f2bf(W[(size_t)(k0 + j) * HC + col]);
    ushort4* q = reinterpret_cast<ushort4*>(Bpk + ((size_t)g * 64 + l) * 8);
    q[0] = make_ushort4(v[0], v[1], v[2], v[3]);
    q[1] = make_ushort4(v[4], v[5], v[6], v[7]);
}

// ---------------- MFMA GEMM: C[M,256](bf16) = A[M,256](bf16) @ B(packed) ----------------
__global__ __launch_bounds__(256) void gemm_mfma_kernel(const unsigned short* __restrict__ A,
                                                        const unsigned short* __restrict__ Bpk,
                                                        unsigned short* __restrict__ C, int M) {
    __shared__ unsigned short As[64 * 256];  // 32 KB, XOR-swizzled rows
    int tid = threadIdx.x;
    int lane = tid & 63, wid = tid >> 6;
    int row0 = blockIdx.x * 64;
#pragma unroll
    for (int i = 0; i < 8; ++i) {
        int idx = tid + i * 256;
        int row = idx >> 5, c16 = idx & 31;
        int grow = row0 + row;
        uint4 v = make_uint4(0u, 0u, 0u, 0u);
        if (grow < M) v = *reinterpret_cast<const uint4*>(A + (size_t)grow * HC + c16 * 8);
        int byteoff = row * 512 + c16 * 16;
        byteoff ^= (row & 7) << 4;
        *reinterpret_cast<uint4*>((char*)As + byteoff) = v;
    }
    __syncthreads();

    f32x4 acc[16];
#pragma unroll
    for (int ct = 0; ct < 16; ++ct) acc[ct] = (f32x4){0.f, 0.f, 0.f, 0.f};

    int mrow = wid * 16 + (lane & 15);
#pragma unroll
    for (int ks = 0; ks < 8; ++ks) {
        int abyte = mrow * 512 + ks * 64 + (lane >> 4) * 16;
        abyte ^= (mrow & 7) << 4;
        bf16x8 a = *reinterpret_cast<const bf16x8*>((char*)As + abyte);
        const unsigned short* bp = Bpk + ((size_t)(ks * 16) * 512 + lane * 8);
#pragma unroll
        for (int ct = 0; ct < 16; ++ct) {
            bf16x8 b = *reinterpret_cast<const bf16x8*>(bp + (size_t)ct * 512);
            acc[ct] = __builtin_amdgcn_mfma_f32_16x16x32_bf16(a, b, acc[ct], 0, 0, 0);
        }
    }
    int crow0 = row0 + wid * 16 + (lane >> 4) * 4;
    int ccol = lane & 15;
#pragma unroll
    for (int ct = 0; ct < 16; ++ct) {
#pragma unroll
        for (int r = 0; r < 4; ++r) {
            int grow = crow0 + r;
            if (grow < M) C[(size_t)grow * HC + ct * 16 + ccol] = f2bf(acc[ct][r]);
        }
    }
}

// ---------------- attention coefficients es/ed per node (bf16 h) ----------------
__global__ __launch_bounds__(256) void esed_kernel(const unsigned short* __restrict__ h,
                                                   const float* __restrict__ avs,
                                                   const float* __restrict__ avd,
                                                   float* __restrict__ es, float* __restrict__ ed) {
    int tid = threadIdx.x;
    int lane = tid & 63, wid = tid >> 6;
    int node = blockIdx.x * 4 + wid;
    if (node >= N_NODES) return;
    int ch0 = lane * 4;
    ushort4 hv = *reinterpret_cast<const ushort4*>(h + (size_t)node * HC + ch0);
    float4 sa = *reinterpret_cast<const float4*>(avs + ch0);
    float4 da = *reinterpret_cast<const float4*>(avd + ch0);
    float h0 = bf2f(hv.x), h1 = bf2f(hv.y), h2 = bf2f(hv.z), h3 = bf2f(hv.w);
    float vs = h0 * sa.x + h1 * sa.y + h2 * sa.z + h3 * sa.w;
    float vd = h0 * da.x + h1 * da.y + h2 * da.z + h3 * da.w;
#pragma unroll
    for (int m = 1; m < 16; m <<= 1) {
        vs += __shfl_xor(vs, m, 64);
        vd += __shfl_xor(vd, m, 64);
    }
    if ((lane & 15) == 0) {
        es[node * NHEAD + (lane >> 4)] = vs;
        ed[node * NHEAD + (lane >> 4)] = vd;
    }
}

// ---------------- CSR build ----------------
__global__ void init_deg_kernel(int* __restrict__ deg) {
    int i = blockIdx.x * blockDim.x + threadIdx.x;
    if (i < N_NODES) deg[i] = 1;  // self loop
}
__global__ void count_edges_kernel(const int* __restrict__ dst, int* __restrict__ deg) {
    int i = blockIdx.x * blockDim.x + threadIdx.x;
    if (i < E_EDGES) atomicAdd(&deg[dst[i]], 1);
}
__global__ __launch_bounds__(1024) void scan1_kernel(const int* __restrict__ deg,
                                                     int* __restrict__ rs, int* __restrict__ bsum) {
    __shared__ int wsum[16];
    int t = threadIdx.x, lane = t & 63, wid = t >> 6;
    int i = blockIdx.x * 1024 + t;
    int v = (i < N_NODES) ? deg[i] : 0;
    int x = v;
#pragma unroll
    for (int off = 1; off < 64; off <<= 1) {
        int y = __shfl_up(x, off, 64);
        if (lane >= off) x += y;
    }
    if (lane == 63) wsum[wid] = x;
    __syncthreads();
    if (wid == 0) {
        int s = (lane < 16) ? wsum[lane] : 0;
#pragma unroll
        for (int off = 1; off < 16; off <<= 1) {
            int y = __shfl_up(s, off, 64);
            if (lane >= off) s += y;
        }
        if (lane < 16) wsum[lane] = s;
    }
    __syncthreads();
    int woff = wid ? wsum[wid - 1] : 0;
    if (i <= N_NODES) rs[i] = woff + x - v;
    if (t == 1023) bsum[blockIdx.x] = wsum[15];
}
__global__ void scan2_kernel(int* __restrict__ bsum, int nb) {
    int l = threadIdx.x;
    int v = (l < nb) ? bsum[l] : 0;
    int x = v;
#pragma unroll
    for (int off = 1; off < 64; off <<= 1) {
        int y = __shfl_up(x, off, 64);
        if (l >= off) x += y;
    }
    if (l < nb) bsum[l] = x - v;
}
__global__ void scan3_kernel(int* __restrict__ rs, const int* __restrict__ bsum,
                             int* __restrict__ cursor) {
    int i = blockIdx.x * blockDim.x + threadIdx.x;
    if (i <= N_NODES) {
        int v = rs[i] + bsum[i >> 10];
        rs[i] = v;
        if (i < N_NODES) cursor[i] = v;
    }
}
__global__ void scatter_self_kernel(int* __restrict__ cursor, int* __restrict__ csr) {
    int i = blockIdx.x * blockDim.x + threadIdx.x;
    if (i < N_NODES) {
        int pos = atomicAdd(&cursor[i], 1);
        csr[pos] = i;
    }
}
__global__ void scatter_edges_kernel(const int* __restrict__ src, const int* __restrict__ dst,
                                     int* __restrict__ cursor, int* __restrict__ csr) {
    int i = blockIdx.x * blockDim.x + threadIdx.x;
    if (i < E_EDGES) {
        int pos = atomicAdd(&cursor[dst[i]], 1);
        csr[pos] = src[i];
    }
}

// ---------------- softmax prep: (m,s) pass stashes e; rescale pass is streaming ----------------
__global__ __launch_bounds__(256) void smprep_kernel(const float* __restrict__ es,
                                                     const float* __restrict__ ed,
                                                     const int* __restrict__ rs,
                                                     const int* __restrict__ csr,
                                                     float* __restrict__ alpha) {
    int tid = threadIdx.x;
    int lane = tid & 63, wid = tid >> 6;
    int node = blockIdx.x * 4 + wid;
    if (node >= N_NODES) return;
    int head = lane >> 4, slot = lane & 15;
    float edn = ed[node * NHEAD + head];
    int beg = rs[node], end = rs[node + 1];
    // finite sentinel: -inf would produce NaN on empty-slot merges (deg<16 common)
    float m = NEG_BIG, s = 0.f;
    for (int i = beg + slot; i < end; i += 16) {
        float e = lrelu(es[csr[i] * NHEAD + head] + edn);
        alpha[(size_t)i * NHEAD + head] = e;   // stash for pass 2 (coalesced)
        float mn = fmaxf(m, e);
        s = s * __expf(m - mn) + __expf(e - mn);
        m = mn;
    }
#pragma unroll
    for (int off = 1; off < 16; off <<= 1) {  // merge within head group (low 4 bits)
        float mo = __shfl_xor(m, off, 64);
        float so = __shfl_xor(s, off, 64);
        float mn = fmaxf(m, mo);
        s = s * __expf(m - mn) + so * __expf(mo - mn);
        m = mn;
    }
    float inv = 1.f / (s + 1e-16f);
    for (int i = beg + slot; i < end; i += 16) {
        float e = alpha[(size_t)i * NHEAD + head];
        alpha[(size_t)i * NHEAD + head] = __expf(e - m) * inv;
    }
}

// ---------------- GAT aggregation v3: 2 nodes/wave, 16B/lane, unroll 4 ----------------
__global__ __launch_bounds__(256) void gat_agg_kernel(const unsigned short* __restrict__ hlin,
                                                      const float* __restrict__ alpha,
                                                      const int* __restrict__ rs,
                                                      const int* __restrict__ csr,
                                                      const float* __restrict__ bias,
                                                      unsigned short* __restrict__ out, int do_relu) {
    int tid = threadIdx.x;
    int lane = tid & 63, wid = tid >> 6;
    // lanes 0-31 -> node A, lanes 32-63 -> node B of this wave
    int node = blockIdx.x * 8 + wid * 2 + (lane >> 5);
    int hl = lane & 31;
    int ch0 = hl * 8;          // 8 channels per lane (16B)
    int head = hl >> 3;
    bool valid = node < N_NODES;
    int beg = valid ? rs[node] : 0;
    int end = valid ? rs[node + 1] : 0;
    float acc[8] = {};
    int idx = beg;
    // per-lane trip counts; exec mask handles A/B divergence
    for (; idx + 4 <= end; idx += 4) {
        int s0 = csr[idx], s1 = csr[idx + 1], s2 = csr[idx + 2], s3 = csr[idx + 3];
        float p0 = alpha[(size_t)idx * NHEAD + head];
        float p1 = alpha[(size_t)(idx + 1) * NHEAD + head];
        float p2 = alpha[(size_t)(idx + 2) * NHEAD + head];
        float p3 = alpha[(size_t)(idx + 3) * NHEAD + head];
        uint4 v0 = *reinterpret_cast<const uint4*>(hlin + (size_t)s0 * HC + ch0);
        uint4 v1 = *reinterpret_cast<const uint4*>(hlin + (size_t)s1 * HC + ch0);
        uint4 v2 = *reinterpret_cast<const uint4*>(hlin + (size_t)s2 * HC + ch0);
        uint4 v3 = *reinterpret_cast<const uint4*>(hlin + (size_t)s3 * HC + ch0);
        accum8(acc, v0, p0);
        accum8(acc, v1, p1);
        accum8(acc, v2, p2);
        accum8(acc, v3, p3);
    }
    for (; idx < end; ++idx) {
        int s0 = csr[idx];
        float p0 = alpha[(size_t)idx * NHEAD + head];
        uint4 v0 = *reinterpret_cast<const uint4*>(hlin + (size_t)s0 * HC + ch0);
        accum8(acc, v0, p0);
    }
    if (!valid) return;
    const float4 bva = *reinterpret_cast<const float4*>(bias + ch0);
    const float4 bvb = *reinterpret_cast<const float4*>(bias + ch0 + 4);
    float o[8];
    o[0] = acc[0] + bva.x; o[1] = acc[1] + bva.y; o[2] = acc[2] + bva.z; o[3] = acc[3] + bva.w;
    o[4] = acc[4] + bvb.x; o[5] = acc[5] + bvb.y; o[6] = acc[6] + bvb.z; o[7] = acc[7] + bvb.w;
    if (do_relu) {
#pragma unroll
        for (int j = 0; j < 8; ++j) o[j] = fmaxf(o[j], 0.f);
    }
    uint4 w;
    w.x = (unsigned int)f2bf(o[0]) | ((unsigned int)f2bf(o[1]) << 16);
    w.y = (unsigned int)f2bf(o[2]) | ((unsigned int)f2bf(o[3]) << 16);
    w.z = (unsigned int)f2bf(o[4]) | ((unsigned int)f2bf(o[5]) << 16);
    w.w = (unsigned int)f2bf(o[6]) | ((unsigned int)f2bf(o[7]) << 16);
    *reinterpret_cast<uint4*>(out + (size_t)node * HC + ch0) = w;
}

// ---------------- BatchNorm stats v2: 8 row-threads x 32 ch-threads, 16B loads ----------------
#define BN_RPB 49
__global__ __launch_bounds__(256) void bn_stats_kernel(const unsigned short* __restrict__ x,
                                                       float* __restrict__ sums) {
    __shared__ float lds[8][512];
    int tid = threadIdx.x;
    int c = tid & 31;   // channels c*8 .. c*8+7
    int rt = tid >> 5;  // 0..7
    int r0 = blockIdx.x * BN_RPB;
    int r1 = min(N_NODES, r0 + BN_RPB);
    int ch = c * 8;
    float s[8] = {}, s2[8] = {};
    for (int r = r0 + rt; r < r1; r += 8) {
        const ushort4* p = reinterpret_cast<const ushort4*>(x + (size_t)r * HC + ch);
        ushort4 va = p[0], vb = p[1];
        unsigned short in[8] = {va.x, va.y, va.z, va.w, vb.x, vb.y, vb.z, vb.w};
#pragma unroll
        for (int j = 0; j < 8; ++j) {
            float v = bf2f(in[j]);
            s[j] += v; s2[j] += v * v;
        }
    }
#pragma unroll
    for (int j = 0; j < 8; ++j) {
        lds[rt][ch + j] = s[j];
        lds[rt][256 + ch + j] = s2[j];
    }
    __syncthreads();
#pragma unroll
    for (int e = tid; e < 512; e += 256) {
        float v = 0.f;
#pragma unroll
        for (int r = 0; r < 8; ++r) v += lds[r][e];
        atomicAdd(&sums[e], v);
    }
}
__global__ void bn_finalize_kernel(const float* __restrict__ sums, const float* __restrict__ g,
                                   const float* __restrict__ b, float* __restrict__ prm) {
    int t = threadIdx.x;  // 256
    float mean = sums[t] / (float)N_NODES;
    float var = sums[HC + t] / (float)N_NODES - mean * mean;
    var = fmaxf(var, 0.f);
    float scale = g[t] * rsqrtf(var + BN_EPS);
    prm[t] = scale;
    prm[HC + t] = b[t] - mean * scale;
}
__global__ __launch_bounds__(256) void bn_apply_relu_kernel(const unsigned short* __restrict__ x,
                                                            const float* __restrict__ prm,
                                                            unsigned short* __restrict__ out) {
    int i = blockIdx.x * blockDim.x + threadIdx.x;
    const int total8 = N_NODES * HC / 8;
    if (i >= total8) return;
    int c0 = (i * 8) & (HC - 1);
    const ushort4* p = reinterpret_cast<const ushort4*>(x + (size_t)i * 8);
    ushort4 va = p[0], vb = p[1];
    unsigned short o[8];
    unsigned short in[8] = {va.x, va.y, va.z, va.w, vb.x, vb.y, vb.z, vb.w};
#pragma unroll
    for (int j = 0; j < 8; ++j) {
        float v = bf2f(in[j]) * prm[c0 + j] + prm[HC + c0 + j];
        o[j] = f2bf(fmaxf(v, 0.f));
    }
    ushort4* q = reinterpret_cast<ushort4*>(out + (size_t)i * 8);
    q[0] = make_ushort4(o[0], o[1], o[2], o[3]);
    q[1] = make_ushort4(o[4], o[5], o[6], o[7]);
}

// ---------------- pooling ----------------
__global__ __launch_bounds__(GG) void graph_ub_kernel(const int* __restrict__ batch,
                                                      int* __restrict__ ub) {
    int g = threadIdx.x;  // 0..127
    int lo = 0, hi = N_NODES;
    while (lo < hi) {
        int mid = (lo + hi) >> 1;
        if (batch[mid] <= g) lo = mid + 1; else hi = mid;
    }
    ub[g] = lo;
}
#define POOL_RPB 32
__global__ __launch_bounds__(256) void pool_kernel(const unsigned short* __restrict__ h,
                                                   const int* __restrict__ batch,
                                                   float* __restrict__ psum) {
    int tid = threadIdx.x;
    int ct = tid & 63;   // channels ct*4 .. ct*4+3
    int rt = tid >> 6;   // 0..3
    int r0 = blockIdx.x * POOL_RPB;
    int r1 = min(N_NODES, r0 + POOL_RPB);
    int ch = ct * 4;
    float a0 = 0.f, a1 = 0.f, a2 = 0.f, a3 = 0.f;
    int gcur = -1;
    for (int r = r0 + rt; r < r1; r += 4) {
        int g = batch[r];
        if (g != gcur) {
            if (gcur >= 0) {
                atomicAdd(&psum[gcur * HC + ch + 0], a0);
                atomicAdd(&psum[gcur * HC + ch + 1], a1);
                atomicAdd(&psum[gcur * HC + ch + 2], a2);
                atomicAdd(&psum[gcur * HC + ch + 3], a3);
            }
            a0 = a1 = a2 = a3 = 0.f; gcur = g;
        }
        ushort4 hv = *reinterpret_cast<const ushort4*>(h + (size_t)r * HC + ch);
        a0 += bf2f(hv.x); a1 += bf2f(hv.y); a2 += bf2f(hv.z); a3 += bf2f(hv.w);
    }
    if (gcur >= 0) {
        atomicAdd(&psum[gcur * HC + ch + 0], a0);
        atomicAdd(&psum[gcur * HC + ch + 1], a1);
        atomicAdd(&psum[gcur * HC + ch + 2], a2);
        atomicAdd(&psum[gcur * HC + ch + 3], a3);
    }
}
__global__ void pool_fin_kernel(const float* __restrict__ psum, const int* __restrict__ ub,
                                float* __restrict__ pooled) {
    int g = blockIdx.x, t = threadIdx.x;
    int c = ub[g] - (g > 0 ? ub[g - 1] : 0);
    float cf = fmaxf((float)c, 1.f);
    pooled[g * HC + t] = psum[g * HC + t] / cf;
}

// ---------------- head ----------------
__global__ __launch_bounds__(256) void bn_head_kernel(const float* __restrict__ pooled,
                                                      const float* __restrict__ g,
                                                      const float* __restrict__ b,
                                                      float* __restrict__ z) {
    int t = threadIdx.x;  // channel
    float s = 0.f, s2 = 0.f;
    for (int r = 0; r < GG; ++r) {
        float v = pooled[r * HC + t];
        s += v; s2 += v * v;
    }
    float mean = s / (float)GG;
    float var = fmaxf(s2 / (float)GG - mean * mean, 0.f);
    float scale = g[t] * rsqrtf(var + BN_EPS);
    float shift = b[t] - mean * scale;
    for (int r = 0; r < GG; ++r)
        z[r * HC + t] = pooled[r * HC + t] * scale + shift;
}
__global__ __launch_bounds__(64) void lin_relu_kernel(const float* __restrict__ X,
                                                      const float* __restrict__ W,
                                                      const float* __restrict__ b,
                                                      float* __restrict__ Y, int K) {
    __shared__ float xr[256];
    int r = blockIdx.x, t = threadIdx.x;
    for (int k = t; k < K; k += 64) xr[k] = X[r * K + k];
    __syncthreads();
    float a = b[t];
    for (int k = 0; k < K; ++k) a += xr[k] * W[k * DENSE + t];
    Y[r * DENSE + t] = fmaxf(a, 0.f);
}
__global__ __launch_bounds__(128) void lin3_softmax_kernel(const float* __restrict__ X,
                                                           const float* __restrict__ W,
                                                           const float* __restrict__ b,
                                                           float* __restrict__ out) {
    int r = threadIdx.x;  // 128 rows
    const float* xr = X + r * DENSE;
    float o0 = b[0], o1 = b[1];
    for (int k = 0; k < DENSE; ++k) {
        o0 += xr[k] * W[k * NCLS + 0];
        o1 += xr[k] * W[k * NCLS + 1];
    }
    o0 = fmaxf(o0, 0.f); o1 = fmaxf(o1, 0.f);
    float mx = fmaxf(o0, o1);
    float e0 = __expf(o0 - mx), e1 = __expf(o1 - mx);
    float inv = 1.f / (e0 + e1);
    out[r * NCLS + 0] = e0 * inv;
    out[r * NCLS + 1] = e1 * inv;
}

extern "C" void kernel_launch(void* const* d_in, const int* in_sizes, int n_in,
                              void* d_out, int out_size, void* d_ws, size_t ws_size,
                              hipStream_t stream) {
    const float* x     = (const float*)d_in[0];
    const int*   ei    = (const int*)d_in[1];
    const int*   srcp  = ei;
    const int*   dstp  = ei + E_EDGES;
    const int*   batch = (const int*)d_in[2];
    const float* W1    = (const float*)d_in[3];
    const float* as1   = (const float*)d_in[4];
    const float* ad1   = (const float*)d_in[5];
    const float* b1    = (const float*)d_in[6];
    const float* Wl    = (const float*)d_in[7];
    const float* asl   = (const float*)d_in[8];
    const float* adl   = (const float*)d_in[9];
    const float* bl    = (const float*)d_in[10];
    const float* bng   = (const float*)d_in[11];
    const float* bnb   = (const float*)d_in[12];
    const float* bn1g  = (const float*)d_in[13];
    const float* bn1b  = (const float*)d_in[14];
    const float* l1W   = (const float*)d_in[15];
    const float* l1b   = (const float*)d_in[16];
    const float* l2W   = (const float*)d_in[17];
    const float* l2b   = (const float*)d_in[18];
    const float* l3W   = (const float*)d_in[19];
    const float* l3b   = (const float*)d_in[20];

    float* outp   = (float*)d_out;            // [128,2]
    float* pooled = outp + GG * NCLS;         // [128,256]

    char* w = (char*)d_ws;
    auto alloc = [&](size_t bytes) -> void* {
        void* p = (void*)w;
        w += (bytes + 255) & ~(size_t)255;
        return p;
    };
    unsigned short* xb  = (unsigned short*)alloc(sizeof(short) * (size_t)N_NODES * HC);
    unsigned short* h0  = (unsigned short*)alloc(sizeof(short) * (size_t)N_NODES * HC);
    unsigned short* h1  = (unsigned short*)alloc(sizeof(short) * (size_t)N_NODES * HC);
    unsigned short* h2  = (unsigned short*)alloc(sizeof(short) * (size_t)N_NODES * HC);
    unsigned short* Bpk = (unsigned short*)alloc(sizeof(short) * 3 * 128 * 64 * 8);
    float* es     = (float*)alloc(sizeof(float) * (size_t)N_NODES * NHEAD);
    float* ed     = (float*)alloc(sizeof(float) * (size_t)N_NODES * NHEAD);
    float* alpha  = (float*)alloc(sizeof(float) * (size_t)E2 * NHEAD);
    int*   rs     = (int*)alloc(sizeof(int) * (N_NODES + 1));
    int*   deg    = (int*)alloc(sizeof(int) * N_NODES);  // reused as cursor
    int*   csr    = (int*)alloc(sizeof(int) * E2);
    int*   bsum   = (int*)alloc(sizeof(int) * 64);
    float* bnsums = (float*)alloc(sizeof(float) * 2 * HC);
    float* bnprm  = (float*)alloc(sizeof(float) * 2 * HC);
    float* psum   = (float*)alloc(sizeof(float) * GG * HC);
    int*   ub     = (int*)alloc(sizeof(int) * GG);
    float* z0     = (float*)alloc(sizeof(float) * GG * HC);
    float* z1     = (float*)alloc(sizeof(float) * GG * DENSE);
    float* z2     = (float*)alloc(sizeof(float) * GG * DENSE);

    const int nblk_nodes = (N_NODES + 255) / 256;
    const int nblk_edges = (E_EDGES + 255) / 256;
    const int nblk_wave4 = (N_NODES + 3) / 4;
    const int nblk_wave8 = (N_NODES + 7) / 8;            // 6250 (2 nodes/wave)
    const int nscan = (N_NODES + 1023) / 1024;           // 49
    const int nblk_bn   = (N_NODES + BN_RPB - 1) / BN_RPB;     // 1021
    const int nblk_pool = (N_NODES + POOL_RPB - 1) / POOL_RPB; // 1563

    // ---- pack weights + convert x ----
    pack_b_kernel<<<128, 64, 0, stream>>>(W1, Bpk);
    pack_b_kernel<<<128, 64, 0, stream>>>(Wl, Bpk + 128 * 64 * 8);
    pack_b_kernel<<<128, 64, 0, stream>>>(Wl + (size_t)HC * HC, Bpk + 2 * 128 * 64 * 8);
    convert_bf16_kernel<<<(N_NODES * HC / 8 + 255) / 256, 256, 0, stream>>>(x, xb, N_NODES * HC / 8);

    // ---- CSR build ----
    init_deg_kernel<<<nblk_nodes, 256, 0, stream>>>(deg);
    count_edges_kernel<<<nblk_edges, 256, 0, stream>>>(dstp, deg);
    scan1_kernel<<<nscan, 1024, 0, stream>>>(deg, rs, bsum);
    scan2_kernel<<<1, 64, 0, stream>>>(bsum, nscan);
    scan3_kernel<<<(N_NODES + 256) / 256, 256, 0, stream>>>(rs, bsum, deg);
    scatter_self_kernel<<<nblk_nodes, 256, 0, stream>>>(deg, csr);
    scatter_edges_kernel<<<nblk_edges, 256, 0, stream>>>(srcp, dstp, deg, csr);

    const int ggrid = (N_NODES + 63) / 64;

    // ---- layer 1 ----
    gemm_mfma_kernel<<<ggrid, 256, 0, stream>>>(xb, Bpk, h1, N_NODES);
    esed_kernel<<<nblk_wave4, 256, 0, stream>>>(h1, as1, ad1, es, ed);
    smprep_kernel<<<nblk_wave4, 256, 0, stream>>>(es, ed, rs, csr, alpha);
    gat_agg_kernel<<<nblk_wave8, 256, 0, stream>>>(h1, alpha, rs, csr, b1, h0, 1);

    // ---- inner layers ----
    for (int i = 0; i < 2; ++i) {
        gemm_mfma_kernel<<<ggrid, 256, 0, stream>>>(h0, Bpk + (size_t)(i + 1) * 128 * 64 * 8, h1, N_NODES);
        esed_kernel<<<nblk_wave4, 256, 0, stream>>>(h1, asl + i * HC, adl + i * HC, es, ed);
        smprep_kernel<<<nblk_wave4, 256, 0, stream>>>(es, ed, rs, csr, alpha);
        gat_agg_kernel<<<nblk_wave8, 256, 0, stream>>>(h1, alpha, rs, csr, bl + i * HC, h2, 0);
        hipMemsetAsync(bnsums, 0, sizeof(float) * 2 * HC, stream);
        bn_stats_kernel<<<nblk_bn, 256, 0, stream>>>(h2, bnsums);
        bn_finalize_kernel<<<1, 256, 0, stream>>>(bnsums, bng + i * HC, bnb + i * HC, bnprm);
        bn_apply_relu_kernel<<<(N_NODES * HC / 8 + 255) / 256, 256, 0, stream>>>(h2, bnprm, h0);
    }

    // ---- pooling ----
    hipMemsetAsync(psum, 0, sizeof(float) * GG * HC, stream);
    graph_ub_kernel<<<1, GG, 0, stream>>>(batch, ub);
    pool_kernel<<<nblk_pool, 256, 0, stream>>>(h0, batch, psum);
    pool_fin_kernel<<<GG, HC, 0, stream>>>(psum, ub, pooled);

    // ---- head ----
    bn_head_kernel<<<1, HC, 0, stream>>>(pooled, bn1g, bn1b, z0);
    lin_relu_kernel<<<GG, 64, 0, stream>>>(z0, l1W, l1b, z1, HC);
    lin_relu_kernel<<<GG, 64, 0, stream>>>(z1, l2W, l2b, z2, DENSE);
    lin3_softmax_kernel<<<1, GG, 0, stream>>>(z2, l3W, l3b, outp);
}

// Round 10
// 607.040 us; speedup vs baseline: 1.0232x; 1.0232x over previous
//
#include <hip/hip_runtime.h>

#define N_NODES 50000
#define E_EDGES 800000
#define E2 (E_EDGES + N_NODES)
#define HC 256
#define NHEAD 4
#define GG 128
#define DENSE 64
#define NCLS 2
#define BN_EPS 1e-5f
#define NEG_SLOPE 0.2f
#define NEG_BIG -1e30f

typedef __attribute__((ext_vector_type(8))) short bf16x8;
typedef __attribute__((ext_vector_type(4))) float f32x4;

__device__ __forceinline__ unsigned short f2bf(float f) {
    unsigned int u = __float_as_uint(f);
    u = (u + 0x7FFFu + ((u >> 16) & 1u)) >> 16;
    return (unsigned short)u;
}
__device__ __forceinline__ float bf2f(unsigned short h) {
    return __uint_as_float(((unsigned int)h) << 16);
}
__device__ __forceinline__ float lrelu(float e) {
    return (e >= 0.f) ? e : NEG_SLOPE * e;
}
// accumulate 8 bf16 (packed in uint4) * w into acc[8]; lo=shift, hi=mask (no cvt)
__device__ __forceinline__ void accum8(float acc[8], uint4 v, float w) {
    acc[0] = fmaf(w, __uint_as_float(v.x << 16), acc[0]);
    acc[1] = fmaf(w, __uint_as_float(v.x & 0xffff0000u), acc[1]);
    acc[2] = fmaf(w, __uint_as_float(v.y << 16), acc[2]);
    acc[3] = fmaf(w, __uint_as_float(v.y & 0xffff0000u), acc[3]);
    acc[4] = fmaf(w, __uint_as_float(v.z << 16), acc[4]);
    acc[5] = fmaf(w, __uint_as_float(v.z & 0xffff0000u), acc[5]);
    acc[6] = fmaf(w, __uint_as_float(v.w << 16), acc[6]);
    acc[7] = fmaf(w, __uint_as_float(v.w & 0xffff0000u), acc[7]);
}

// ---------------- fp32 -> bf16 conversion (8 elems/thread) ----------------
__global__ __launch_bounds__(256) void convert_bf16_kernel(const float* __restrict__ in,
                                                           unsigned short* __restrict__ out,
                                                           int n8) {
    int i = blockIdx.x * blockDim.x + threadIdx.x;
    if (i >= n8) return;
    const float4* p = reinterpret_cast<const float4*>(in + (size_t)i * 8);
    float4 a = p[0], b = p[1];
    ushort4 lo = make_ushort4(f2bf(a.x), f2bf(a.y), f2bf(a.z), f2bf(a.w));
    ushort4 hi = make_ushort4(f2bf(b.x), f2bf(b.y), f2bf(b.z), f2bf(b.w));
    ushort4* q = reinterpret_cast<ushort4*>(out + (size_t)i * 8);
    q[0] = lo; q[1] = hi;
}

// ---------------- pack W [256,256] fp32 into MFMA b-fragment order, bf16 ----------------
__global__ __launch_bounds__(64) void pack_b_kernel(const float* __restrict__ W,
                                                    unsigned short* __restrict__ Bpk) {
    int l = threadIdx.x;
    int g = blockIdx.x;
    int ks = g >> 4, ct = g & 15;
    int col = ct * 16 + (l & 15);
    int k0 = ks * 32 + (l >> 4) * 8;
    unsigned short v[8];
#pragma unroll
    for (int j = 0; j < 8; ++j) v[j] = f2bf(W[(size_t)(k0 + j) * HC + col]);
    ushort4* q = reinterpret_cast<ushort4*>(Bpk + ((size_t)g * 64 + l) * 8);
    q[0] = make_ushort4(v[0], v[1], v[2], v[3]);
    q[1] = make_ushort4(v[4], v[5], v[6], v[7]);
}

// ---------------- MFMA GEMM (optional fused BN affine+ReLU on A during staging) ----------------
__global__ __launch_bounds__(256) void gemm_mfma_kernel(const unsigned short* __restrict__ A,
                                                        const unsigned short* __restrict__ Bpk,
                                                        const float* __restrict__ prm,
                                                        unsigned short* __restrict__ C, int M) {
    __shared__ unsigned short As[64 * 256];  // 32 KB, XOR-swizzled rows
    int tid = threadIdx.x;
    int lane = tid & 63, wid = tid >> 6;
    int row0 = blockIdx.x * 64;
#pragma unroll
    for (int i = 0; i < 8; ++i) {
        int idx = tid + i * 256;
        int row = idx >> 5, c16 = idx & 31;
        int grow = row0 + row;
        uint4 v = make_uint4(0u, 0u, 0u, 0u);
        if (grow < M) v = *reinterpret_cast<const uint4*>(A + (size_t)grow * HC + c16 * 8);
        if (prm) {
            int ch = c16 * 8;
            const float4 s0 = *reinterpret_cast<const float4*>(prm + ch);
            const float4 s1 = *reinterpret_cast<const float4*>(prm + ch + 4);
            const float4 t0 = *reinterpret_cast<const float4*>(prm + HC + ch);
            const float4 t1 = *reinterpret_cast<const float4*>(prm + HC + ch + 4);
            float f0 = fmaxf(fmaf(__uint_as_float(v.x << 16),          s0.x, t0.x), 0.f);
            float f1 = fmaxf(fmaf(__uint_as_float(v.x & 0xffff0000u),  s0.y, t0.y), 0.f);
            float f2 = fmaxf(fmaf(__uint_as_float(v.y << 16),          s0.z, t0.z), 0.f);
            float f3 = fmaxf(fmaf(__uint_as_float(v.y & 0xffff0000u),  s0.w, t0.w), 0.f);
            float f4 = fmaxf(fmaf(__uint_as_float(v.z << 16),          s1.x, t1.x), 0.f);
            float f5 = fmaxf(fmaf(__uint_as_float(v.z & 0xffff0000u),  s1.y, t1.y), 0.f);
            float f6 = fmaxf(fmaf(__uint_as_float(v.w << 16),          s1.z, t1.z), 0.f);
            float f7 = fmaxf(fmaf(__uint_as_float(v.w & 0xffff0000u),  s1.w, t1.w), 0.f);
            v.x = (unsigned int)f2bf(f0) | ((unsigned int)f2bf(f1) << 16);
            v.y = (unsigned int)f2bf(f2) | ((unsigned int)f2bf(f3) << 16);
            v.z = (unsigned int)f2bf(f4) | ((unsigned int)f2bf(f5) << 16);
            v.w = (unsigned int)f2bf(f6) | ((unsigned int)f2bf(f7) << 16);
        }
        int byteoff = row * 512 + c16 * 16;
        byteoff ^= (row & 7) << 4;
        *reinterpret_cast<uint4*>((char*)As + byteoff) = v;
    }
    __syncthreads();

    f32x4 acc[16];
#pragma unroll
    for (int ct = 0; ct < 16; ++ct) acc[ct] = (f32x4){0.f, 0.f, 0.f, 0.f};

    int mrow = wid * 16 + (lane & 15);
#pragma unroll
    for (int ks = 0; ks < 8; ++ks) {
        int abyte = mrow * 512 + ks * 64 + (lane >> 4) * 16;
        abyte ^= (mrow & 7) << 4;
        bf16x8 a = *reinterpret_cast<const bf16x8*>((char*)As + abyte);
        const unsigned short* bp = Bpk + ((size_t)(ks * 16) * 512 + lane * 8);
#pragma unroll
        for (int ct = 0; ct < 16; ++ct) {
            bf16x8 b = *reinterpret_cast<const bf16x8*>(bp + (size_t)ct * 512);
            acc[ct] = __builtin_amdgcn_mfma_f32_16x16x32_bf16(a, b, acc[ct], 0, 0, 0);
        }
    }
    int crow0 = row0 + wid * 16 + (lane >> 4) * 4;
    int ccol = lane & 15;
#pragma unroll
    for (int ct = 0; ct < 16; ++ct) {
#pragma unroll
        for (int r = 0; r < 4; ++r) {
            int grow = crow0 + r;
            if (grow < M) C[(size_t)grow * HC + ct * 16 + ccol] = f2bf(acc[ct][r]);
        }
    }
}

// ---------------- attention coefficients es/ed per node (bf16 h) ----------------
__global__ __launch_bounds__(256) void esed_kernel(const unsigned short* __restrict__ h,
                                                   const float* __restrict__ avs,
                                                   const float* __restrict__ avd,
                                                   float* __restrict__ es, float* __restrict__ ed) {
    int tid = threadIdx.x;
    int lane = tid & 63, wid = tid >> 6;
    int node = blockIdx.x * 4 + wid;
    if (node >= N_NODES) return;
    int ch0 = lane * 4;
    ushort4 hv = *reinterpret_cast<const ushort4*>(h + (size_t)node * HC + ch0);
    float4 sa = *reinterpret_cast<const float4*>(avs + ch0);
    float4 da = *reinterpret_cast<const float4*>(avd + ch0);
    float h0 = bf2f(hv.x), h1 = bf2f(hv.y), h2 = bf2f(hv.z), h3 = bf2f(hv.w);
    float vs = h0 * sa.x + h1 * sa.y + h2 * sa.z + h3 * sa.w;
    float vd = h0 * da.x + h1 * da.y + h2 * da.z + h3 * da.w;
#pragma unroll
    for (int m = 1; m < 16; m <<= 1) {
        vs += __shfl_xor(vs, m, 64);
        vd += __shfl_xor(vd, m, 64);
    }
    if ((lane & 15) == 0) {
        es[node * NHEAD + (lane >> 4)] = vs;
        ed[node * NHEAD + (lane >> 4)] = vd;
    }
}

// ---------------- CSR build ----------------
__global__ void init_deg_kernel(int* __restrict__ deg) {
    int i = blockIdx.x * blockDim.x + threadIdx.x;
    if (i < N_NODES) deg[i] = 1;  // self loop
}
__global__ void count_edges_kernel(const int* __restrict__ dst, int* __restrict__ deg) {
    int i = blockIdx.x * blockDim.x + threadIdx.x;
    if (i < E_EDGES) atomicAdd(&deg[dst[i]], 1);
}
__global__ __launch_bounds__(1024) void scan1_kernel(const int* __restrict__ deg,
                                                     int* __restrict__ rs, int* __restrict__ bsum) {
    __shared__ int wsum[16];
    int t = threadIdx.x, lane = t & 63, wid = t >> 6;
    int i = blockIdx.x * 1024 + t;
    int v = (i < N_NODES) ? deg[i] : 0;
    int x = v;
#pragma unroll
    for (int off = 1; off < 64; off <<= 1) {
        int y = __shfl_up(x, off, 64);
        if (lane >= off) x += y;
    }
    if (lane == 63) wsum[wid] = x;
    __syncthreads();
    if (wid == 0) {
        int s = (lane < 16) ? wsum[lane] : 0;
#pragma unroll
        for (int off = 1; off < 16; off <<= 1) {
            int y = __shfl_up(s, off, 64);
            if (lane >= off) s += y;
        }
        if (lane < 16) wsum[lane] = s;
    }
    __syncthreads();
    int woff = wid ? wsum[wid - 1] : 0;
    if (i <= N_NODES) rs[i] = woff + x - v;
    if (t == 1023) bsum[blockIdx.x] = wsum[15];
}
__global__ void scan2_kernel(int* __restrict__ bsum, int nb) {
    int l = threadIdx.x;
    int v = (l < nb) ? bsum[l] : 0;
    int x = v;
#pragma unroll
    for (int off = 1; off < 64; off <<= 1) {
        int y = __shfl_up(x, off, 64);
        if (l >= off) x += y;
    }
    if (l < nb) bsum[l] = x - v;
}
// scan3 + self-loop scatter fused: csr[v] = i (self loop first), cursor = v+1
__global__ void scan3_kernel(int* __restrict__ rs, const int* __restrict__ bsum,
                             int* __restrict__ cursor, int* __restrict__ csr) {
    int i = blockIdx.x * blockDim.x + threadIdx.x;
    if (i <= N_NODES) {
        int v = rs[i] + bsum[i >> 10];
        rs[i] = v;
        if (i < N_NODES) {
            csr[v] = i;
            cursor[i] = v + 1;
        }
    }
}
__global__ void scatter_edges_kernel(const int* __restrict__ src, const int* __restrict__ dst,
                                     int* __restrict__ cursor, int* __restrict__ csr) {
    int i = blockIdx.x * blockDim.x + threadIdx.x;
    if (i < E_EDGES) {
        int pos = atomicAdd(&cursor[dst[i]], 1);
        csr[pos] = src[i];
    }
}

// ---------------- softmax prep: (m,s) pass stashes e; rescale pass is streaming ----------------
__global__ __launch_bounds__(256) void smprep_kernel(const float* __restrict__ es,
                                                     const float* __restrict__ ed,
                                                     const int* __restrict__ rs,
                                                     const int* __restrict__ csr,
                                                     float* __restrict__ alpha) {
    int tid = threadIdx.x;
    int lane = tid & 63, wid = tid >> 6;
    int node = blockIdx.x * 4 + wid;
    if (node >= N_NODES) return;
    int head = lane >> 4, slot = lane & 15;
    float edn = ed[node * NHEAD + head];
    int beg = rs[node], end = rs[node + 1];
    // finite sentinel: -inf would produce NaN on empty-slot merges (deg<16 common)
    float m = NEG_BIG, s = 0.f;
    for (int i = beg + slot; i < end; i += 16) {
        float e = lrelu(es[csr[i] * NHEAD + head] + edn);
        alpha[(size_t)i * NHEAD + head] = e;   // stash for pass 2 (coalesced)
        float mn = fmaxf(m, e);
        s = s * __expf(m - mn) + __expf(e - mn);
        m = mn;
    }
#pragma unroll
    for (int off = 1; off < 16; off <<= 1) {  // merge within head group (low 4 bits)
        float mo = __shfl_xor(m, off, 64);
        float so = __shfl_xor(s, off, 64);
        float mn = fmaxf(m, mo);
        s = s * __expf(m - mn) + so * __expf(mo - mn);
        m = mn;
    }
    float inv = 1.f / (s + 1e-16f);
    for (int i = beg + slot; i < end; i += 16) {
        float e = alpha[(size_t)i * NHEAD + head];
        alpha[(size_t)i * NHEAD + head] = __expf(e - m) * inv;
    }
}

// ---------------- GAT aggregation: 2 nodes/wave, 16B/lane, unroll 8/4/1 ----------------
__global__ __launch_bounds__(256) void gat_agg_kernel(const unsigned short* __restrict__ hlin,
                                                      const float* __restrict__ alpha,
                                                      const int* __restrict__ rs,
                                                      const int* __restrict__ csr,
                                                      const float* __restrict__ bias,
                                                      unsigned short* __restrict__ out, int do_relu) {
    int tid = threadIdx.x;
    int lane = tid & 63, wid = tid >> 6;
    int node = blockIdx.x * 8 + wid * 2 + (lane >> 5);
    int hl = lane & 31;
    int ch0 = hl * 8;          // 8 channels per lane (16B)
    int head = hl >> 3;
    bool valid = node < N_NODES;
    int beg = valid ? rs[node] : 0;
    int end = valid ? rs[node + 1] : 0;
    float acc[8] = {};
    int idx = beg;
    for (; idx + 8 <= end; idx += 8) {
        int si[8]; float pi[8];
#pragma unroll
        for (int j = 0; j < 8; ++j) {
            si[j] = csr[idx + j];
            pi[j] = alpha[(size_t)(idx + j) * NHEAD + head];
        }
        uint4 v[8];
#pragma unroll
        for (int j = 0; j < 8; ++j)
            v[j] = *reinterpret_cast<const uint4*>(hlin + (size_t)si[j] * HC + ch0);
#pragma unroll
        for (int j = 0; j < 8; ++j) accum8(acc, v[j], pi[j]);
    }
    if (idx + 4 <= end) {
        int s0 = csr[idx], s1 = csr[idx + 1], s2 = csr[idx + 2], s3 = csr[idx + 3];
        float p0 = alpha[(size_t)idx * NHEAD + head];
        float p1 = alpha[(size_t)(idx + 1) * NHEAD + head];
        float p2 = alpha[(size_t)(idx + 2) * NHEAD + head];
        float p3 = alpha[(size_t)(idx + 3) * NHEAD + head];
        uint4 v0 = *reinterpret_cast<const uint4*>(hlin + (size_t)s0 * HC + ch0);
        uint4 v1 = *reinterpret_cast<const uint4*>(hlin + (size_t)s1 * HC + ch0);
        uint4 v2 = *reinterpret_cast<const uint4*>(hlin + (size_t)s2 * HC + ch0);
        uint4 v3 = *reinterpret_cast<const uint4*>(hlin + (size_t)s3 * HC + ch0);
        accum8(acc, v0, p0);
        accum8(acc, v1, p1);
        accum8(acc, v2, p2);
        accum8(acc, v3, p3);
        idx += 4;
    }
    for (; idx < end; ++idx) {
        int s0 = csr[idx];
        float p0 = alpha[(size_t)idx * NHEAD + head];
        uint4 v0 = *reinterpret_cast<const uint4*>(hlin + (size_t)s0 * HC + ch0);
        accum8(acc, v0, p0);
    }
    if (!valid) return;
    const float4 bva = *reinterpret_cast<const float4*>(bias + ch0);
    const float4 bvb = *reinterpret_cast<const float4*>(bias + ch0 + 4);
    float o[8];
    o[0] = acc[0] + bva.x; o[1] = acc[1] + bva.y; o[2] = acc[2] + bva.z; o[3] = acc[3] + bva.w;
    o[4] = acc[4] + bvb.x; o[5] = acc[5] + bvb.y; o[6] = acc[6] + bvb.z; o[7] = acc[7] + bvb.w;
    if (do_relu) {
#pragma unroll
        for (int j = 0; j < 8; ++j) o[j] = fmaxf(o[j], 0.f);
    }
    uint4 w;
    w.x = (unsigned int)f2bf(o[0]) | ((unsigned int)f2bf(o[1]) << 16);
    w.y = (unsigned int)f2bf(o[2]) | ((unsigned int)f2bf(o[3]) << 16);
    w.z = (unsigned int)f2bf(o[4]) | ((unsigned int)f2bf(o[5]) << 16);
    w.w = (unsigned int)f2bf(o[6]) | ((unsigned int)f2bf(o[7]) << 16);
    *reinterpret_cast<uint4*>(out + (size_t)node * HC + ch0) = w;
}

// ---------------- BatchNorm stats: 8 row-threads x 32 ch-threads, 16B loads ----------------
#define BN_RPB 49
__global__ __launch_bounds__(256) void bn_stats_kernel(const unsigned short* __restrict__ x,
                                                       float* __restrict__ sums) {
    __shared__ float lds[8][512];
    int tid = threadIdx.x;
    int c = tid & 31;   // channels c*8 .. c*8+7
    int rt = tid >> 5;  // 0..7
    int r0 = blockIdx.x * BN_RPB;
    int r1 = min(N_NODES, r0 + BN_RPB);
    int ch = c * 8;
    float s[8] = {}, s2[8] = {};
    for (int r = r0 + rt; r < r1; r += 8) {
        const ushort4* p = reinterpret_cast<const ushort4*>(x + (size_t)r * HC + ch);
        ushort4 va = p[0], vb = p[1];
        unsigned short in[8] = {va.x, va.y, va.z, va.w, vb.x, vb.y, vb.z, vb.w};
#pragma unroll
        for (int j = 0; j < 8; ++j) {
            float v = bf2f(in[j]);
            s[j] += v; s2[j] += v * v;
        }
    }
#pragma unroll
    for (int j = 0; j < 8; ++j) {
        lds[rt][ch + j] = s[j];
        lds[rt][256 + ch + j] = s2[j];
    }
    __syncthreads();
#pragma unroll
    for (int e = tid; e < 512; e += 256) {
        float v = 0.f;
#pragma unroll
        for (int r = 0; r < 8; ++r) v += lds[r][e];
        atomicAdd(&sums[e], v);
    }
}
__global__ void bn_finalize_kernel(const float* __restrict__ sums, const float* __restrict__ g,
                                   const float* __restrict__ b, float* __restrict__ prm) {
    int t = threadIdx.x;  // 256
    float mean = sums[t] / (float)N_NODES;
    float var = sums[HC + t] / (float)N_NODES - mean * mean;
    var = fmaxf(var, 0.f);
    float scale = g[t] * rsqrtf(var + BN_EPS);
    prm[t] = scale;
    prm[HC + t] = b[t] - mean * scale;
}

// ---------------- pooling (fused BN affine + ReLU on h2) ----------------
__global__ __launch_bounds__(GG) void graph_ub_kernel(const int* __restrict__ batch,
                                                      int* __restrict__ ub) {
    int g = threadIdx.x;  // 0..127
    int lo = 0, hi = N_NODES;
    while (lo < hi) {
        int mid = (lo + hi) >> 1;
        if (batch[mid] <= g) lo = mid + 1; else hi = mid;
    }
    ub[g] = lo;
}
#define POOL_RPB 32
__global__ __launch_bounds__(256) void pool_kernel(const unsigned short* __restrict__ h,
                                                   const float* __restrict__ prm,
                                                   const int* __restrict__ batch,
                                                   float* __restrict__ psum) {
    int tid = threadIdx.x;
    int ct = tid & 63;   // channels ct*4 .. ct*4+3
    int rt = tid >> 6;   // 0..3
    int r0 = blockIdx.x * POOL_RPB;
    int r1 = min(N_NODES, r0 + POOL_RPB);
    int ch = ct * 4;
    const float4 sc = *reinterpret_cast<const float4*>(prm + ch);
    const float4 sh = *reinterpret_cast<const float4*>(prm + HC + ch);
    float a0 = 0.f, a1 = 0.f, a2 = 0.f, a3 = 0.f;
    int gcur = -1;
    for (int r = r0 + rt; r < r1; r += 4) {
        int g = batch[r];
        if (g != gcur) {
            if (gcur >= 0) {
                atomicAdd(&psum[gcur * HC + ch + 0], a0);
                atomicAdd(&psum[gcur * HC + ch + 1], a1);
                atomicAdd(&psum[gcur * HC + ch + 2], a2);
                atomicAdd(&psum[gcur * HC + ch + 3], a3);
            }
            a0 = a1 = a2 = a3 = 0.f; gcur = g;
        }
        ushort4 hv = *reinterpret_cast<const ushort4*>(h + (size_t)r * HC + ch);
        a0 += fmaxf(fmaf(bf2f(hv.x), sc.x, sh.x), 0.f);
        a1 += fmaxf(fmaf(bf2f(hv.y), sc.y, sh.y), 0.f);
        a2 += fmaxf(fmaf(bf2f(hv.z), sc.z, sh.z), 0.f);
        a3 += fmaxf(fmaf(bf2f(hv.w), sc.w, sh.w), 0.f);
    }
    if (gcur >= 0) {
        atomicAdd(&psum[gcur * HC + ch + 0], a0);
        atomicAdd(&psum[gcur * HC + ch + 1], a1);
        atomicAdd(&psum[gcur * HC + ch + 2], a2);
        atomicAdd(&psum[gcur * HC + ch + 3], a3);
    }
}
__global__ void pool_fin_kernel(const float* __restrict__ psum, const int* __restrict__ ub,
                                float* __restrict__ pooled) {
    int g = blockIdx.x, t = threadIdx.x;
    int c = ub[g] - (g > 0 ? ub[g - 1] : 0);
    float cf = fmaxf((float)c, 1.f);
    pooled[g * HC + t] = psum[g * HC + t] / cf;
}

// ---------------- head ----------------
__global__ __launch_bounds__(256) void bn_head_kernel(const float* __restrict__ pooled,
                                                      const float* __restrict__ g,
                                                      const float* __restrict__ b,
                                                      float* __restrict__ z) {
    int t = threadIdx.x;  // channel
    float s = 0.f, s2 = 0.f;
    for (int r = 0; r < GG; ++r) {
        float v = pooled[r * HC + t];
        s += v; s2 += v * v;
    }
    float mean = s / (float)GG;
    float var = fmaxf(s2 / (float)GG - mean * mean, 0.f);
    float scale = g[t] * rsqrtf(var + BN_EPS);
    float shift = b[t] - mean * scale;
    for (int r = 0; r < GG; ++r)
        z[r * HC + t] = pooled[r * HC + t] * scale + shift;
}
__global__ __launch_bounds__(64) void lin_relu_kernel(const float* __restrict__ X,
                                                      const float* __restrict__ W,
                                                      const float* __restrict__ b,
                                                      float* __restrict__ Y, int K) {
    __shared__ float xr[256];
    int r = blockIdx.x, t = threadIdx.x;
    for (int k = t; k < K; k += 64) xr[k] = X[r * K + k];
    __syncthreads();
    float a = b[t];
    for (int k = 0; k < K; ++k) a += xr[k] * W[k * DENSE + t];
    Y[r * DENSE + t] = fmaxf(a, 0.f);
}
__global__ __launch_bounds__(128) void lin3_softmax_kernel(const float* __restrict__ X,
                                                           const float* __restrict__ W,
                                                           const float* __restrict__ b,
                                                           float* __restrict__ out) {
    int r = threadIdx.x;  // 128 rows
    const float* xr = X + r * DENSE;
    float o0 = b[0], o1 = b[1];
    for (int k = 0; k < DENSE; ++k) {
        o0 += xr[k] * W[k * NCLS + 0];
        o1 += xr[k] * W[k * NCLS + 1];
    }
    o0 = fmaxf(o0, 0.f); o1 = fmaxf(o1, 0.f);
    float mx = fmaxf(o0, o1);
    float e0 = __expf(o0 - mx), e1 = __expf(o1 - mx);
    float inv = 1.f / (e0 + e1);
    out[r * NCLS + 0] = e0 * inv;
    out[r * NCLS + 1] = e1 * inv;
}

extern "C" void kernel_launch(void* const* d_in, const int* in_sizes, int n_in,
                              void* d_out, int out_size, void* d_ws, size_t ws_size,
                              hipStream_t stream) {
    const float* x     = (const float*)d_in[0];
    const int*   ei    = (const int*)d_in[1];
    const int*   srcp  = ei;
    const int*   dstp  = ei + E_EDGES;
    const int*   batch = (const int*)d_in[2];
    const float* W1    = (const float*)d_in[3];
    const float* as1   = (const float*)d_in[4];
    const float* ad1   = (const float*)d_in[5];
    const float* b1    = (const float*)d_in[6];
    const float* Wl    = (const float*)d_in[7];
    const float* asl   = (const float*)d_in[8];
    const float* adl   = (const float*)d_in[9];
    const float* bl    = (const float*)d_in[10];
    const float* bng   = (const float*)d_in[11];
    const float* bnb   = (const float*)d_in[12];
    const float* bn1g  = (const float*)d_in[13];
    const float* bn1b  = (const float*)d_in[14];
    const float* l1W   = (const float*)d_in[15];
    const float* l1b   = (const float*)d_in[16];
    const float* l2W   = (const float*)d_in[17];
    const float* l2b   = (const float*)d_in[18];
    const float* l3W   = (const float*)d_in[19];
    const float* l3b   = (const float*)d_in[20];

    float* outp   = (float*)d_out;            // [128,2]
    float* pooled = outp + GG * NCLS;         // [128,256]

    char* w = (char*)d_ws;
    auto alloc = [&](size_t bytes) -> void* {
        void* p = (void*)w;
        w += (bytes + 255) & ~(size_t)255;
        return p;
    };
    unsigned short* xb  = (unsigned short*)alloc(sizeof(short) * (size_t)N_NODES * HC);
    unsigned short* h0  = (unsigned short*)alloc(sizeof(short) * (size_t)N_NODES * HC);
    unsigned short* h1  = (unsigned short*)alloc(sizeof(short) * (size_t)N_NODES * HC);
    unsigned short* h2  = (unsigned short*)alloc(sizeof(short) * (size_t)N_NODES * HC);
    unsigned short* Bpk = (unsigned short*)alloc(sizeof(short) * 3 * 128 * 64 * 8);
    float* es     = (float*)alloc(sizeof(float) * (size_t)N_NODES * NHEAD);
    float* ed     = (float*)alloc(sizeof(float) * (size_t)N_NODES * NHEAD);
    float* alpha  = (float*)alloc(sizeof(float) * (size_t)E2 * NHEAD);
    int*   rs     = (int*)alloc(sizeof(int) * (N_NODES + 1));
    int*   deg    = (int*)alloc(sizeof(int) * N_NODES);  // reused as cursor
    int*   csr    = (int*)alloc(sizeof(int) * E2);
    int*   bsum   = (int*)alloc(sizeof(int) * 64);
    float* bnsums = (float*)alloc(sizeof(float) * 2 * HC);
    float* bnprm  = (float*)alloc(sizeof(float) * 2 * HC);
    float* psum   = (float*)alloc(sizeof(float) * GG * HC);
    int*   ub     = (int*)alloc(sizeof(int) * GG);
    float* z0     = (float*)alloc(sizeof(float) * GG * HC);
    float* z1     = (float*)alloc(sizeof(float) * GG * DENSE);
    float* z2     = (float*)alloc(sizeof(float) * GG * DENSE);

    const int nblk_nodes = (N_NODES + 255) / 256;
    const int nblk_edges = (E_EDGES + 255) / 256;
    const int nblk_wave4 = (N_NODES + 3) / 4;
    const int nblk_wave8 = (N_NODES + 7) / 8;            // 6250 (2 nodes/wave)
    const int nscan = (N_NODES + 1023) / 1024;           // 49
    const int nblk_bn   = (N_NODES + BN_RPB - 1) / BN_RPB;     // 1021
    const int nblk_pool = (N_NODES + POOL_RPB - 1) / POOL_RPB; // 1563

    // ---- pack weights + convert x ----
    pack_b_kernel<<<128, 64, 0, stream>>>(W1, Bpk);
    pack_b_kernel<<<128, 64, 0, stream>>>(Wl, Bpk + 128 * 64 * 8);
    pack_b_kernel<<<128, 64, 0, stream>>>(Wl + (size_t)HC * HC, Bpk + 2 * 128 * 64 * 8);
    convert_bf16_kernel<<<(N_NODES * HC / 8 + 255) / 256, 256, 0, stream>>>(x, xb, N_NODES * HC / 8);

    // ---- CSR build ----
    init_deg_kernel<<<nblk_nodes, 256, 0, stream>>>(deg);
    count_edges_kernel<<<nblk_edges, 256, 0, stream>>>(dstp, deg);
    scan1_kernel<<<nscan, 1024, 0, stream>>>(deg, rs, bsum);
    scan2_kernel<<<1, 64, 0, stream>>>(bsum, nscan);
    scan3_kernel<<<(N_NODES + 256) / 256, 256, 0, stream>>>(rs, bsum, deg, csr);
    scatter_edges_kernel<<<nblk_edges, 256, 0, stream>>>(srcp, dstp, deg, csr);

    const int ggrid = (N_NODES + 63) / 64;

    // ---- layer 1: h0 = relu(gat(x)) ----
    gemm_mfma_kernel<<<ggrid, 256, 0, stream>>>(xb, Bpk, nullptr, h1, N_NODES);
    esed_kernel<<<nblk_wave4, 256, 0, stream>>>(h1, as1, ad1, es, ed);
    smprep_kernel<<<nblk_wave4, 256, 0, stream>>>(es, ed, rs, csr, alpha);
    gat_agg_kernel<<<nblk_wave8, 256, 0, stream>>>(h1, alpha, rs, csr, b1, h0, 1);

    // ---- inner layer 0: h2 = gat(gemm(h0)); BN0 stats -> bnprm ----
    gemm_mfma_kernel<<<ggrid, 256, 0, stream>>>(h0, Bpk + 128 * 64 * 8, nullptr, h1, N_NODES);
    esed_kernel<<<nblk_wave4, 256, 0, stream>>>(h1, asl, adl, es, ed);
    smprep_kernel<<<nblk_wave4, 256, 0, stream>>>(es, ed, rs, csr, alpha);
    gat_agg_kernel<<<nblk_wave8, 256, 0, stream>>>(h1, alpha, rs, csr, bl, h2, 0);
    hipMemsetAsync(bnsums, 0, sizeof(float) * 2 * HC, stream);
    bn_stats_kernel<<<nblk_bn, 256, 0, stream>>>(h2, bnsums);
    bn_finalize_kernel<<<1, 256, 0, stream>>>(bnsums, bng, bnb, bnprm);

    // ---- inner layer 1: gemm reads h2 with fused BN0 affine+relu ----
    gemm_mfma_kernel<<<ggrid, 256, 0, stream>>>(h2, Bpk + 2 * 128 * 64 * 8, bnprm, h1, N_NODES);
    esed_kernel<<<nblk_wave4, 256, 0, stream>>>(h1, asl + HC, adl + HC, es, ed);
    smprep_kernel<<<nblk_wave4, 256, 0, stream>>>(es, ed, rs, csr, alpha);
    gat_agg_kernel<<<nblk_wave8, 256, 0, stream>>>(h1, alpha, rs, csr, bl + HC, h2, 0);
    hipMemsetAsync(bnsums, 0, sizeof(float) * 2 * HC, stream);
    bn_stats_kernel<<<nblk_bn, 256, 0, stream>>>(h2, bnsums);
    bn_finalize_kernel<<<1, 256, 0, stream>>>(bnsums, bng + HC, bnb + HC, bnprm);

    // ---- pooling (fused BN1 affine+relu) ----
    hipMemsetAsync(psum, 0, sizeof(float) * GG * HC, stream);
    graph_ub_kernel<<<1, GG, 0, stream>>>(batch, ub);
    pool_kernel<<<nblk_pool, 256, 0, stream>>>(h2, bnprm, batch, psum);
    pool_fin_kernel<<<GG, HC, 0, stream>>>(psum, ub, pooled);

    // ---- head ----
    bn_head_kernel<<<1, HC, 0, stream>>>(pooled, bn1g, bn1b, z0);
    lin_relu_kernel<<<GG, 64, 0, stream>>>(z0, l1W, l1b, z1, HC);
    lin_relu_kernel<<<GG, 64, 0, stream>>>(z1, l2W, l2b, z2, DENSE);
    lin3_softmax_kernel<<<1, GG, 0, stream>>>(z2, l3W, l3b, outp);
}